// Round 6
// baseline (371.194 us; speedup 1.0000x reference)
//
#include <hip/hip_runtime.h>
#include <math.h>

// B=65536, F=512, K=1299.
// R1-R3: atomics->partials, batched rows (main ~43us est). R4/R5/R7: cache
// hints neutral-to-negative. R6: 2x occupancy neutral -> not latency-bound.
// R8/R10: bucketed (center-once) regressed +28-32us BOTH with and without
// ILP -> bucketed structural costs (2 extra dispatches, random-2KB-row DRAM
// inefficiency, imbalance) exceed the center-miss saving. Accounting now
// closed: controllable ~47us = main ~35 (partial center thrash, ~10us
// recoverable but every mechanism costs more) + reduce ~4 + dispatch ~8.
// R11 (this): keep R6 main loop EXACTLY; fuse the reduce via tag-flag
// completion (no zero-init needed under ws poisoning): each block writes
// partials[bid], release-stores 64-bit runtime tag (f(input[0],centers[0]))
// to tags[bid]; block 0 polls tags with agent-scope acquire loads (L1
// bypass -> no stale lines), sums, writes out[0]. Saves the reduce dispatch
// (~4-8us). Predict 192 -> 186-189. Neutral/regress -> revert + declare.

#define F_DIM 512
#define ROWS_PER_WAVE 4
#define WAVES_PER_BLOCK 4
#define NUM_BLOCKS 4096   // 4096 blk * 4 waves * 4 rows = 65536 rows exactly

typedef float fx4 __attribute__((ext_vector_type(4)));
typedef unsigned long long u64;

__global__ __launch_bounds__(256) void fused_prediction_loss_kernel(
    const float* __restrict__ input,    // (B, F)  -- streamed, zero reuse
    const float* __restrict__ factor,   // (B,)
    const int*   __restrict__ label,    // (B,)
    const float* __restrict__ centers,  // (K, F)  -- 2.66 MB, partial L2 reuse
    float* __restrict__ out,            // [0]=loss, [1..B]=predict_a
    float* __restrict__ partials,       // (NUM_BLOCKS,) in ws
    u64*   __restrict__ tags)           // (NUM_BLOCKS,) in ws
{
    const int wave = threadIdx.x >> 6;
    const int lane = threadIdx.x & 63;
    const int b0 = (blockIdx.x * WAVES_PER_BLOCK + wave) * ROWS_PER_WAVE;

    // --- label indices (scalarized) ---
    int c[ROWS_PER_WAVE];
    #pragma unroll
    for (int r = 0; r < ROWS_PER_WAVE; ++r)
        c[r] = __builtin_amdgcn_readfirstlane(label[b0 + r]);

    // --- 8 input loads, non-temporal (stream, no reuse) ---
    fx4 a0[ROWS_PER_WAVE], a1[ROWS_PER_WAVE];
    #pragma unroll
    for (int r = 0; r < ROWS_PER_WAVE; ++r) {
        const fx4* __restrict__ ip =
            (const fx4*)(input + (size_t)(b0 + r) * F_DIM);
        a0[r] = __builtin_nontemporal_load(ip + lane);
        a1[r] = __builtin_nontemporal_load(ip + lane + 64);
    }
    // --- 8 center loads, normal caching ---
    fx4 w0[ROWS_PER_WAVE], w1[ROWS_PER_WAVE];
    #pragma unroll
    for (int r = 0; r < ROWS_PER_WAVE; ++r) {
        const fx4* __restrict__ cp =
            (const fx4*)(centers + (size_t)c[r] * F_DIM);
        w0[r] = cp[lane];
        w1[r] = cp[lane + 64];
    }

    // --- 4 independent partial dots ---
    float dot[ROWS_PER_WAVE];
    #pragma unroll
    for (int r = 0; r < ROWS_PER_WAVE; ++r) {
        dot[r] = a0[r].x * w0[r].x + a0[r].y * w0[r].y
               + a0[r].z * w0[r].z + a0[r].w * w0[r].w
               + a1[r].x * w1[r].x + a1[r].y * w1[r].y
               + a1[r].z * w1[r].z + a1[r].w * w1[r].w;
    }

    // --- batched butterfly: 6 steps x 4 independent chains ---
    #pragma unroll
    for (int off = 32; off > 0; off >>= 1) {
        #pragma unroll
        for (int r = 0; r < ROWS_PER_WAVE; ++r)
            dot[r] += __shfl_xor(dot[r], off, 64);
    }
    // every lane holds all 4 complete dots.

    const int sel = lane & 3;
    float v = dot[0];
    #pragma unroll
    for (int r = 1; r < ROWS_PER_WAVE; ++r)
        v = (sel == r) ? dot[r] : v;

    const float pa = 12.0f * tanhf(v);

    float contrib = 0.0f;
    if (lane < ROWS_PER_WAVE) {
        out[1 + b0 + lane] = pa;
        const float d  = pa - factor[b0 + lane];
        const float ad = fabsf(d);
        contrib = (ad < 1.0f) ? 0.5f * d * d : (ad - 0.5f);
    }
    contrib += __shfl_xor(contrib, 2, 64);
    contrib += __shfl_xor(contrib, 1, 64);

    __shared__ float sh[WAVES_PER_BLOCK];
    if (lane == 0) sh[wave] = contrib;
    __syncthreads();

    // runtime tag: poison in ws cannot collide except with 2^-64 luck
    const u64 tag = ((((u64)__float_as_uint(input[0])) << 32)
                     ^ (u64)__float_as_uint(centers[0]))
                    ^ 0x9E3779B97F4A7C15ULL;

    if (threadIdx.x == 0) {
        partials[blockIdx.x] =
            ((sh[0] + sh[1]) + (sh[2] + sh[3])) * (1.0f / 65536.0f);
        // release: partial visible in L2 before tag appears
        __hip_atomic_store(&tags[blockIdx.x], tag,
                           __ATOMIC_RELEASE, __HIP_MEMORY_SCOPE_AGENT);
    }

    // --- block 0 doubles as the reducer: poll tags, sum, write loss ---
    if (blockIdx.x == 0) {
        float s = 0.0f;
        #pragma unroll 1
        for (int k = 0; k < NUM_BLOCKS / 256; ++k) {
            const int i = threadIdx.x + k * 256;
            while (__hip_atomic_load(&tags[i], __ATOMIC_ACQUIRE,
                                     __HIP_MEMORY_SCOPE_AGENT) != tag) {
                __builtin_amdgcn_s_sleep(1);   // polite spin, cut L2 poll traffic
            }
            // agent-scope load: bypass L1 so no stale line from this kernel
            s += __hip_atomic_load(&partials[i], __ATOMIC_RELAXED,
                                   __HIP_MEMORY_SCOPE_AGENT);
        }
        #pragma unroll
        for (int off = 32; off > 0; off >>= 1)
            s += __shfl_xor(s, off, 64);

        __shared__ float sh2[WAVES_PER_BLOCK];
        if (lane == 0) sh2[wave] = s;
        __syncthreads();   // block-uniform branch: safe
        if (threadIdx.x == 0)
            out[0] = (sh2[0] + sh2[1]) + (sh2[2] + sh2[3]);
    }
}

// ---------------- fallback two-kernel path (proven 192us) ----------------

__global__ __launch_bounds__(256) void prediction_loss_kernel(
    const float* __restrict__ input,
    const float* __restrict__ factor,
    const int*   __restrict__ label,
    const float* __restrict__ centers,
    float* __restrict__ out,
    float* __restrict__ partials)
{
    const int wave = threadIdx.x >> 6;
    const int lane = threadIdx.x & 63;
    const int b0 = (blockIdx.x * WAVES_PER_BLOCK + wave) * ROWS_PER_WAVE;

    int c[ROWS_PER_WAVE];
    #pragma unroll
    for (int r = 0; r < ROWS_PER_WAVE; ++r)
        c[r] = __builtin_amdgcn_readfirstlane(label[b0 + r]);

    fx4 a0[ROWS_PER_WAVE], a1[ROWS_PER_WAVE];
    #pragma unroll
    for (int r = 0; r < ROWS_PER_WAVE; ++r) {
        const fx4* __restrict__ ip =
            (const fx4*)(input + (size_t)(b0 + r) * F_DIM);
        a0[r] = __builtin_nontemporal_load(ip + lane);
        a1[r] = __builtin_nontemporal_load(ip + lane + 64);
    }
    fx4 w0[ROWS_PER_WAVE], w1[ROWS_PER_WAVE];
    #pragma unroll
    for (int r = 0; r < ROWS_PER_WAVE; ++r) {
        const fx4* __restrict__ cp =
            (const fx4*)(centers + (size_t)c[r] * F_DIM);
        w0[r] = cp[lane];
        w1[r] = cp[lane + 64];
    }

    float dot[ROWS_PER_WAVE];
    #pragma unroll
    for (int r = 0; r < ROWS_PER_WAVE; ++r) {
        dot[r] = a0[r].x * w0[r].x + a0[r].y * w0[r].y
               + a0[r].z * w0[r].z + a0[r].w * w0[r].w
               + a1[r].x * w1[r].x + a1[r].y * w1[r].y
               + a1[r].z * w1[r].z + a1[r].w * w1[r].w;
    }

    #pragma unroll
    for (int off = 32; off > 0; off >>= 1) {
        #pragma unroll
        for (int r = 0; r < ROWS_PER_WAVE; ++r)
            dot[r] += __shfl_xor(dot[r], off, 64);
    }

    const int sel = lane & 3;
    float v = dot[0];
    #pragma unroll
    for (int r = 1; r < ROWS_PER_WAVE; ++r)
        v = (sel == r) ? dot[r] : v;

    const float pa = 12.0f * tanhf(v);

    float contrib = 0.0f;
    if (lane < ROWS_PER_WAVE) {
        out[1 + b0 + lane] = pa;
        const float d  = pa - factor[b0 + lane];
        const float ad = fabsf(d);
        contrib = (ad < 1.0f) ? 0.5f * d * d : (ad - 0.5f);
    }
    contrib += __shfl_xor(contrib, 2, 64);
    contrib += __shfl_xor(contrib, 1, 64);

    __shared__ float sh[WAVES_PER_BLOCK];
    if (lane == 0) sh[wave] = contrib;
    __syncthreads();
    if (threadIdx.x == 0)
        partials[blockIdx.x] =
            ((sh[0] + sh[1]) + (sh[2] + sh[3])) * (1.0f / 65536.0f);
}

__global__ __launch_bounds__(256) void reduce_partials_kernel(
    const float* __restrict__ partials, float* __restrict__ out)
{
    __shared__ float sh[4];
    const int wave = threadIdx.x >> 6;
    const int lane = threadIdx.x & 63;

    float s = 0.0f;
    #pragma unroll
    for (int i = 0; i < NUM_BLOCKS / 256; ++i)
        s += partials[threadIdx.x + i * 256];

    #pragma unroll
    for (int off = 32; off > 0; off >>= 1)
        s += __shfl_xor(s, off, 64);

    if (lane == 0) sh[wave] = s;
    __syncthreads();
    if (threadIdx.x == 0)
        out[0] = (sh[0] + sh[1]) + (sh[2] + sh[3]);
}

// ---------------- launch ----------------

extern "C" void kernel_launch(void* const* d_in, const int* in_sizes, int n_in,
                              void* d_out, int out_size, void* d_ws, size_t ws_size,
                              hipStream_t stream) {
    const float* input   = (const float*)d_in[0];
    const float* factor  = (const float*)d_in[1];
    const int*   label   = (const int*)d_in[2];
    const float* centers = (const float*)d_in[3];
    float* out = (float*)d_out;

    char* ws = (char*)d_ws;
    u64*   tags     = (u64*)ws;                          // NUM_BLOCKS * 8 B
    float* partials = (float*)(ws + NUM_BLOCKS * 8);     // NUM_BLOCKS * 4 B
    const size_t needed = NUM_BLOCKS * 12;

    if (ws_size >= needed) {
        fused_prediction_loss_kernel<<<NUM_BLOCKS, 256, 0, stream>>>(
            input, factor, label, centers, out, partials, tags);
    } else {
        float* p = (float*)d_ws;
        prediction_loss_kernel<<<NUM_BLOCKS, 256, 0, stream>>>(
            input, factor, label, centers, out, p);
        reduce_partials_kernel<<<1, 256, 0, stream>>>(p, out);
    }
}

// Round 7
// 189.412 us; speedup vs baseline: 1.9597x; 1.9597x over previous
//
#include <hip/hip_runtime.h>
#include <math.h>

// B=65536, F=512, K=1299.
// R1-R3: atomics->partials, batched rows. R4/R5/R7: cache hints neutral/neg.
// R6: 2x occupancy neutral -> not latency-bound. R8/R10: bucketed center-once
// regressed (+28-32us): structural costs > center-miss saving.
// R11: fused reduce via acquire/release agent atomics -> 212us kernel (5x).
// Mechanism: agent-scope ACQUIRE emits L2 invalidate, RELEASE emits L2
// writeback on non-coherent multi-XCD gfx950; 4096 releases + poll-loop
// invalidates = continuous cache maintenance. WRITE_SIZE ~900KB (no
// amplification) -> stall cost, not traffic. New datum: FETCH=76.5MB only
// (input largely L3-resident; harness fill doesn't allocate L3).
// R12 (this): same fusion, RELAXED-only protocol. Pack {tag32|payload-f32}
// in ONE 64-bit atomic word -> payload needs no separate ordering; relaxed
// agent atomics are performed at the coherent point with NO cache
// maintenance (same mechanism as cross-XCD atomicAdd). Tag from runtime
// input/centers bits; poison collision 2^-32/slot. Predict fused ~45-55us,
// total ~185-188. If ~212 again -> polling structure is the cost, revert+declare.

#define F_DIM 512
#define ROWS_PER_WAVE 4
#define WAVES_PER_BLOCK 4
#define NUM_BLOCKS 4096   // 4096 blk * 4 waves * 4 rows = 65536 rows exactly

typedef float fx4 __attribute__((ext_vector_type(4)));
typedef unsigned long long u64;
typedef unsigned int u32;

__global__ __launch_bounds__(256) void fused_prediction_loss_kernel(
    const float* __restrict__ input,    // (B, F)  -- streamed
    const float* __restrict__ factor,   // (B,)
    const int*   __restrict__ label,    // (B,)
    const float* __restrict__ centers,  // (K, F)  -- 2.66 MB
    float* __restrict__ out,            // [0]=loss, [1..B]=predict_a
    u64*   __restrict__ slots)          // (NUM_BLOCKS,) packed {tag|payload}
{
    const int wave = threadIdx.x >> 6;
    const int lane = threadIdx.x & 63;
    const int b0 = (blockIdx.x * WAVES_PER_BLOCK + wave) * ROWS_PER_WAVE;

    // --- label indices (scalarized) ---
    int c[ROWS_PER_WAVE];
    #pragma unroll
    for (int r = 0; r < ROWS_PER_WAVE; ++r)
        c[r] = __builtin_amdgcn_readfirstlane(label[b0 + r]);

    // --- 8 input loads, non-temporal (stream, no reuse) ---
    fx4 a0[ROWS_PER_WAVE], a1[ROWS_PER_WAVE];
    #pragma unroll
    for (int r = 0; r < ROWS_PER_WAVE; ++r) {
        const fx4* __restrict__ ip =
            (const fx4*)(input + (size_t)(b0 + r) * F_DIM);
        a0[r] = __builtin_nontemporal_load(ip + lane);
        a1[r] = __builtin_nontemporal_load(ip + lane + 64);
    }
    // --- 8 center loads, normal caching ---
    fx4 w0[ROWS_PER_WAVE], w1[ROWS_PER_WAVE];
    #pragma unroll
    for (int r = 0; r < ROWS_PER_WAVE; ++r) {
        const fx4* __restrict__ cp =
            (const fx4*)(centers + (size_t)c[r] * F_DIM);
        w0[r] = cp[lane];
        w1[r] = cp[lane + 64];
    }

    // --- 4 independent partial dots ---
    float dot[ROWS_PER_WAVE];
    #pragma unroll
    for (int r = 0; r < ROWS_PER_WAVE; ++r) {
        dot[r] = a0[r].x * w0[r].x + a0[r].y * w0[r].y
               + a0[r].z * w0[r].z + a0[r].w * w0[r].w
               + a1[r].x * w1[r].x + a1[r].y * w1[r].y
               + a1[r].z * w1[r].z + a1[r].w * w1[r].w;
    }

    // --- batched butterfly: 6 steps x 4 independent chains ---
    #pragma unroll
    for (int off = 32; off > 0; off >>= 1) {
        #pragma unroll
        for (int r = 0; r < ROWS_PER_WAVE; ++r)
            dot[r] += __shfl_xor(dot[r], off, 64);
    }

    const int sel = lane & 3;
    float v = dot[0];
    #pragma unroll
    for (int r = 1; r < ROWS_PER_WAVE; ++r)
        v = (sel == r) ? dot[r] : v;

    const float pa = 12.0f * tanhf(v);

    float contrib = 0.0f;
    if (lane < ROWS_PER_WAVE) {
        out[1 + b0 + lane] = pa;
        const float d  = pa - factor[b0 + lane];
        const float ad = fabsf(d);
        contrib = (ad < 1.0f) ? 0.5f * d * d : (ad - 0.5f);
    }
    contrib += __shfl_xor(contrib, 2, 64);
    contrib += __shfl_xor(contrib, 1, 64);

    __shared__ float sh[WAVES_PER_BLOCK];
    if (lane == 0) sh[wave] = contrib;
    __syncthreads();

    // runtime tag: workspace poison cannot fake it except 2^-32 per slot
    const u32 tag32 = __float_as_uint(input[0])
                    ^ (__float_as_uint(centers[0]) * 2654435761u)
                    ^ 0x9E3779B9u;

    if (threadIdx.x == 0) {
        const float partial =
            ((sh[0] + sh[1]) + (sh[2] + sh[3])) * (1.0f / 65536.0f);
        const u64 packed = ((u64)tag32 << 32) | (u64)__float_as_uint(partial);
        // relaxed agent atomic: performed at coherent point, NO cache maint.
        __hip_atomic_store(&slots[blockIdx.x], packed,
                           __ATOMIC_RELAXED, __HIP_MEMORY_SCOPE_AGENT);
    }

    // --- block 0 doubles as the reducer: poll packed slots, sum, write loss
    if (blockIdx.x == 0) {
        float s = 0.0f;
        #pragma unroll 1
        for (int k = 0; k < NUM_BLOCKS / 256; ++k) {
            const int i = threadIdx.x + k * 256;
            u64 v;
            for (;;) {
                v = __hip_atomic_load(&slots[i], __ATOMIC_RELAXED,
                                      __HIP_MEMORY_SCOPE_AGENT);
                if ((u32)(v >> 32) == tag32) break;
                __builtin_amdgcn_s_sleep(2);   // polite spin
            }
            s += __uint_as_float((u32)v);      // payload rode inside the word
        }
        #pragma unroll
        for (int off = 32; off > 0; off >>= 1)
            s += __shfl_xor(s, off, 64);

        __shared__ float sh2[WAVES_PER_BLOCK];
        if (lane == 0) sh2[wave] = s;
        __syncthreads();   // block-uniform branch: safe
        if (threadIdx.x == 0)
            out[0] = (sh2[0] + sh2[1]) + (sh2[2] + sh2[3]);
    }
}

// ---------------- fallback two-kernel path (proven 192us) ----------------

__global__ __launch_bounds__(256) void prediction_loss_kernel(
    const float* __restrict__ input,
    const float* __restrict__ factor,
    const int*   __restrict__ label,
    const float* __restrict__ centers,
    float* __restrict__ out,
    float* __restrict__ partials)
{
    const int wave = threadIdx.x >> 6;
    const int lane = threadIdx.x & 63;
    const int b0 = (blockIdx.x * WAVES_PER_BLOCK + wave) * ROWS_PER_WAVE;

    int c[ROWS_PER_WAVE];
    #pragma unroll
    for (int r = 0; r < ROWS_PER_WAVE; ++r)
        c[r] = __builtin_amdgcn_readfirstlane(label[b0 + r]);

    fx4 a0[ROWS_PER_WAVE], a1[ROWS_PER_WAVE];
    #pragma unroll
    for (int r = 0; r < ROWS_PER_WAVE; ++r) {
        const fx4* __restrict__ ip =
            (const fx4*)(input + (size_t)(b0 + r) * F_DIM);
        a0[r] = __builtin_nontemporal_load(ip + lane);
        a1[r] = __builtin_nontemporal_load(ip + lane + 64);
    }
    fx4 w0[ROWS_PER_WAVE], w1[ROWS_PER_WAVE];
    #pragma unroll
    for (int r = 0; r < ROWS_PER_WAVE; ++r) {
        const fx4* __restrict__ cp =
            (const fx4*)(centers + (size_t)c[r] * F_DIM);
        w0[r] = cp[lane];
        w1[r] = cp[lane + 64];
    }

    float dot[ROWS_PER_WAVE];
    #pragma unroll
    for (int r = 0; r < ROWS_PER_WAVE; ++r) {
        dot[r] = a0[r].x * w0[r].x + a0[r].y * w0[r].y
               + a0[r].z * w0[r].z + a0[r].w * w0[r].w
               + a1[r].x * w1[r].x + a1[r].y * w1[r].y
               + a1[r].z * w1[r].z + a1[r].w * w1[r].w;
    }

    #pragma unroll
    for (int off = 32; off > 0; off >>= 1) {
        #pragma unroll
        for (int r = 0; r < ROWS_PER_WAVE; ++r)
            dot[r] += __shfl_xor(dot[r], off, 64);
    }

    const int sel = lane & 3;
    float v = dot[0];
    #pragma unroll
    for (int r = 1; r < ROWS_PER_WAVE; ++r)
        v = (sel == r) ? dot[r] : v;

    const float pa = 12.0f * tanhf(v);

    float contrib = 0.0f;
    if (lane < ROWS_PER_WAVE) {
        out[1 + b0 + lane] = pa;
        const float d  = pa - factor[b0 + lane];
        const float ad = fabsf(d);
        contrib = (ad < 1.0f) ? 0.5f * d * d : (ad - 0.5f);
    }
    contrib += __shfl_xor(contrib, 2, 64);
    contrib += __shfl_xor(contrib, 1, 64);

    __shared__ float sh[WAVES_PER_BLOCK];
    if (lane == 0) sh[wave] = contrib;
    __syncthreads();
    if (threadIdx.x == 0)
        partials[blockIdx.x] =
            ((sh[0] + sh[1]) + (sh[2] + sh[3])) * (1.0f / 65536.0f);
}

__global__ __launch_bounds__(256) void reduce_partials_kernel(
    const float* __restrict__ partials, float* __restrict__ out)
{
    __shared__ float sh[4];
    const int wave = threadIdx.x >> 6;
    const int lane = threadIdx.x & 63;

    float s = 0.0f;
    #pragma unroll
    for (int i = 0; i < NUM_BLOCKS / 256; ++i)
        s += partials[threadIdx.x + i * 256];

    #pragma unroll
    for (int off = 32; off > 0; off >>= 1)
        s += __shfl_xor(s, off, 64);

    if (lane == 0) sh[wave] = s;
    __syncthreads();
    if (threadIdx.x == 0)
        out[0] = (sh[0] + sh[1]) + (sh[2] + sh[3]);
}

// ---------------- launch ----------------

extern "C" void kernel_launch(void* const* d_in, const int* in_sizes, int n_in,
                              void* d_out, int out_size, void* d_ws, size_t ws_size,
                              hipStream_t stream) {
    const float* input   = (const float*)d_in[0];
    const float* factor  = (const float*)d_in[1];
    const int*   label   = (const int*)d_in[2];
    const float* centers = (const float*)d_in[3];
    float* out = (float*)d_out;

    u64* slots = (u64*)d_ws;                      // NUM_BLOCKS * 8 B
    const size_t needed = NUM_BLOCKS * 8;

    if (ws_size >= needed) {
        fused_prediction_loss_kernel<<<NUM_BLOCKS, 256, 0, stream>>>(
            input, factor, label, centers, out, slots);
    } else {
        float* p = (float*)d_ws;
        prediction_loss_kernel<<<NUM_BLOCKS, 256, 0, stream>>>(
            input, factor, label, centers, out, p);
        reduce_partials_kernel<<<1, 256, 0, stream>>>(p, out);
    }
}